// Round 6
// baseline (245.978 us; speedup 1.0000x reference)
//
#include <hip/hip_runtime.h>

typedef __bf16 bf16;
typedef __attribute__((ext_vector_type(8))) __bf16 bf16x8;
typedef __attribute__((ext_vector_type(4))) __bf16 bf16x4;
typedef __attribute__((ext_vector_type(4))) float f32x4;

#define MFMA16(a, b, c) __builtin_amdgcn_mfma_f32_16x16x32_bf16((a), (b), (c), 0, 0, 0)

#define S_LEN 4096
#define NHEAD 12
#define EMB   768
#define NEGV  (-1e30f)

// async global->LDS, 16B per lane. LDS dest = wave-uniform base + lane*16 (linear);
// swizzled layouts are achieved by pre-swizzling the per-lane GLOBAL source addr.
__device__ __forceinline__ void gload16(const bf16* g, bf16* l) {
  __builtin_amdgcn_global_load_lds((const __attribute__((address_space(1))) void*)g,
                                   (__attribute__((address_space(3))) void*)l, 16, 0, 0);
}

// ---------------- kernel 0: f32 -> bf16 convert (optionally scaled) -------------
__global__ __launch_bounds__(256) void cvt_kernel(const float* __restrict__ x,
                                                  bf16* __restrict__ o, int n8, float scale) {
  int i = blockIdx.x * 256 + threadIdx.x;
  if (i >= n8) return;
  const float4* p = (const float4*)(x + (size_t)i * 8);
  float4 a = p[0], b = p[1];
  bf16x8 v;
  v[0] = (bf16)(a.x * scale); v[1] = (bf16)(a.y * scale);
  v[2] = (bf16)(a.z * scale); v[3] = (bf16)(a.w * scale);
  v[4] = (bf16)(b.x * scale); v[5] = (bf16)(b.y * scale);
  v[6] = (bf16)(b.z * scale); v[7] = (bf16)(b.w * scale);
  *(bf16x8*)(o + (size_t)i * 8) = v;
}

// three weight matrices in one launch; which = blockIdx.y, Wq gets 1/sqrt(D) folded
__global__ __launch_bounds__(256) void cvt3_kernel(const float* __restrict__ w0,
                                                   const float* __restrict__ w1,
                                                   const float* __restrict__ w2,
                                                   bf16* __restrict__ o, int n8) {
  int which = blockIdx.y;
  const float* src = (which == 0) ? w0 : (which == 1) ? w1 : w2;
  float scale = (which == 0) ? 0.125f : 1.0f;
  int i = blockIdx.x * 256 + threadIdx.x;
  if (i >= n8) return;
  const float4* p = (const float4*)(src + (size_t)i * 8);
  float4 a = p[0], b = p[1];
  bf16x8 v;
  v[0] = (bf16)(a.x * scale); v[1] = (bf16)(a.y * scale);
  v[2] = (bf16)(a.z * scale); v[3] = (bf16)(a.w * scale);
  v[4] = (bf16)(b.x * scale); v[5] = (bf16)(b.y * scale);
  v[6] = (bf16)(b.z * scale); v[7] = (bf16)(b.w * scale);
  *(bf16x8*)(o + ((size_t)which * n8 + i) * 8) = v;
}

// attention_mask -> additive float (-1e30 where masked, 0 elsewhere)
__global__ __launch_bounds__(256) void amask_cvt(const float* __restrict__ am,
                                                 float* __restrict__ o, int n) {
  int i = blockIdx.x * 256 + threadIdx.x;
  if (i < n) o[i] = (am[i] != 0.f) ? -1e30f : 0.f;
}

// ---------------- kernel 1: fused QKV GEMM  out = X @ W^T + bias ----------------
// 128x128 tile, BK=64, 4 waves. Double-buffered global_load_lds staging (T3-min
// 2-phase): stage(t+1) issued BEFORE compute(t); ONE __syncthreads per K-step,
// after the MFMAs — loads fly during compute. Vectorized LDS epilogue.
__global__ __launch_bounds__(256) void qkv_gemm(const bf16* __restrict__ Xb, const bf16* __restrict__ Wb,
                                                const float* __restrict__ bq, const float* __restrict__ bk,
                                                const float* __restrict__ bv,
                                                bf16* __restrict__ Qo, bf16* __restrict__ Ko,
                                                bf16* __restrict__ Vt) {
  __shared__ union SM {
    struct { bf16 a[2][128 * 64]; bf16 b2[2][128 * 64]; } st;  // 64KB double-buffered staging
    bf16 c[128 * 130];                                          // epilogue buffer (overlaps)
  } sm;
  const int tid = threadIdx.x;
  const int l = tid & 63, w = tid >> 6;
  const int ln = l & 15, g = l >> 4;
  const int wm = w >> 1, wn = w & 1;
  const int m0 = blockIdx.x * 128;
  const int n0 = blockIdx.y * 128;

  const f32x4 zero4 = {0.f, 0.f, 0.f, 0.f};
  f32x4 acc[4][4];
#pragma unroll
  for (int i = 0; i < 4; ++i)
#pragma unroll
    for (int j = 0; j < 4; ++j) acc[i][j] = zero4;

  int srow[4], sslot[4];
#pragma unroll
  for (int i = 0; i < 4; ++i) {
    const int G = w * 256 + i * 64 + l;      // granule id 0..1023
    srow[i] = G >> 3;
    sslot[i] = (G & 7) ^ (srow[i] & 7);
  }

  auto stage = [&](int sb, int kt) {
    const int k0 = kt * 64;
#pragma unroll
    for (int i = 0; i < 4; ++i) {
      gload16(Xb + (size_t)(m0 + srow[i]) * 768 + k0 + sslot[i] * 8, &sm.st.a[sb][(w * 256 + i * 64) * 8]);
      gload16(Wb + (size_t)(n0 + srow[i]) * 768 + k0 + sslot[i] * 8, &sm.st.b2[sb][(w * 256 + i * 64) * 8]);
    }
  };

  stage(0, 0);
  __syncthreads();

  int buf = 0;
  for (int kt = 0; kt < 12; ++kt, buf ^= 1) {
    if (kt < 11) stage(buf ^ 1, kt + 1);
#pragma unroll
    for (int kc = 0; kc < 2; ++kc) {
      bf16x8 af[4], bfr[4];
#pragma unroll
      for (int i = 0; i < 4; ++i) {
        int ra = wm * 64 + i * 16 + ln;
        af[i] = *(const bf16x8*)(&sm.st.a[buf][ra * 64 + ((kc * 4 + g) ^ (ra & 7)) * 8]);
        int rb = wn * 64 + i * 16 + ln;
        bfr[i] = *(const bf16x8*)(&sm.st.b2[buf][rb * 64 + ((kc * 4 + g) ^ (rb & 7)) * 8]);
      }
#pragma unroll
      for (int mi = 0; mi < 4; ++mi)
#pragma unroll
        for (int ni = 0; ni < 4; ++ni)
          acc[mi][ni] = MFMA16(af[mi], bfr[ni], acc[mi][ni]);
    }
    __syncthreads();
  }

  // ----- epilogue: all outputs through LDS, vectorized stores -----
  const int which = n0 / 768;           // 0=Q 1=K 2=V
  const int h0 = (n0 % 768) >> 6;
  const int b = m0 >> 12;
  const int h = h0 + wn;
  const float bsc = (which == 0) ? 0.125f : 1.0f;
  const float* bias = (which == 0) ? bq : (which == 1) ? bk : bv;
  float bvv[4];
#pragma unroll
  for (int ni = 0; ni < 4; ++ni) bvv[ni] = bias[h * 64 + ni * 16 + ln] * bsc;

#pragma unroll
  for (int mi = 0; mi < 4; ++mi)
#pragma unroll
    for (int ni = 0; ni < 4; ++ni)
#pragma unroll
      for (int r = 0; r < 4; ++r) {
        int sl = wm * 64 + mi * 16 + g * 4 + r;
        sm.c[sl * 130 + wn * 64 + ni * 16 + ln] = (bf16)(acc[mi][ni][r] + bvv[ni]);
      }
  __syncthreads();

  if (which < 2) {
    bf16* dst = (which == 0) ? Qo : Ko;
#pragma unroll
    for (int it = 0; it < 8; ++it) {
      int gid = it * 256 + tid;
      int sl = gid >> 4, cg = gid & 15;
      int hh = h0 + (cg >> 3);
      bf16x8 v8 = *(const bf16x8*)(&sm.c[sl * 130 + cg * 8]);
      *(bf16x8*)(dst + ((size_t)(b * NHEAD + hh) * S_LEN + (m0 & 4095) + sl) * 64 + (cg & 7) * 8) = v8;
    }
  } else {
#pragma unroll
    for (int it = 0; it < 4; ++it) {
      int d = it * 32 + (tid >> 3);
      int scp = tid & 7;
      int hh = h0 + (d >> 6);
      bf16x8 o0, o1;
#pragma unroll
      for (int i2 = 0; i2 < 8; ++i2) o0[i2] = sm.c[(scp * 16 + i2) * 130 + d];
#pragma unroll
      for (int i2 = 0; i2 < 8; ++i2) o1[i2] = sm.c[(scp * 16 + 8 + i2) * 130 + d];
      bf16* dp = Vt + ((size_t)(b * NHEAD + hh) * 64 + (d & 63)) * S_LEN + (m0 & 4095) + scp * 16;
      *(bf16x8*)dp = o0;
      *(bf16x8*)(dp + 8) = o1;
    }
  }
}

// ---------------- kernel 2: banded flash attention, BARRIER-FREE ----------------
// Block = 64 queries x (b,h), 4 waves x 16 queries, fully independent waves.
// K/V are L2-resident (1MB per bh, XCD swizzle keeps 3 bh per XCD): load MFMA
// fragments DIRECTLY global->register — no LDS staging, no __syncthreads at all.
// Per-wave pipeline: V-frag loads issued before QK (covered by QK+softmax);
// next-tile K-frags prefetched after QK (covered by softmax+PV).
__global__ __launch_bounds__(256) void attn_kernel(const bf16* __restrict__ Qb, const bf16* __restrict__ Kb,
                                                   const bf16* __restrict__ Vtb,
                                                   const float* __restrict__ Amadd,
                                                   const unsigned char* __restrict__ imask,
                                                   float* __restrict__ out) {
  __shared__ bf16 Pt[4][16 * 64];   // per-wave P^T [q][key], 8B-granule XOR swizzle
  const int tid = threadIdx.x;
  const int l = tid & 63, w = tid >> 6;
  const int ln = l & 15, g = l >> 4;
  // XCD swizzle: 1536 blocks = 8 * 192, bijective; each XCD gets 3 contiguous bh
  const int orig = blockIdx.x;
  const int lb = (orig & 7) * 192 + (orig >> 3);
  const int qc = lb & 63, bh = lb >> 6;
  const int b = bh / NHEAD, h = bh % NHEAD;
  const int q0 = qc * 64;
  const int qg = q0 + w * 16 + ln;

  const size_t qoff = ((size_t)bh * S_LEN + qg) * 64;
  const bf16x8 qf0 = *(const bf16x8*)(Qb + qoff + g * 8);
  const bf16x8 qf1 = *(const bf16x8*)(Qb + qoff + 32 + g * 8);

  const bf16* Kbh = Kb + (size_t)bh * S_LEN * 64;
  const bf16* Vbh = Vtb + (size_t)bh * 64 * S_LEN;
  const float* Ab = Amadd + b * S_LEN;

  const f32x4 zero4 = {0.f, 0.f, 0.f, 0.f};
  f32x4 acc[4];
#pragma unroll
  for (int i = 0; i < 4; ++i) acc[i] = zero4;
  float mrun = -1e38f, lrun = 0.f;

  const int t_lo = (q0 >= 256) ? 0 : ((256 - q0) >> 6);
  int t_hi = (S_LEN + 256 - q0) >> 6;
  if (t_hi > 9) t_hi = 9;

  // prefetch K fragments for first tile (A-operand: lane ln = key row, 16B/lane)
  bf16x8 kf[4][2];
  {
    const int tj0 = q0 - 256 + t_lo * 64;
#pragma unroll
    for (int mi = 0; mi < 4; ++mi)
#pragma unroll
      for (int kc = 0; kc < 2; ++kc)
        kf[mi][kc] = *(const bf16x8*)(Kbh + (size_t)(tj0 + mi * 16 + ln) * 64 + kc * 32 + g * 8);
  }

  bf16* PtW = &Pt[w][0];
  for (int t = t_lo; t < t_hi; ++t) {
    const int tj0 = q0 - 256 + t * 64;

    // issue V^T frag loads now; consumed after softmax (latency covered)
    bf16x8 vf[4][2];
#pragma unroll
    for (int ds2 = 0; ds2 < 4; ++ds2)
#pragma unroll
      for (int kc = 0; kc < 2; ++kc)
        vf[ds2][kc] = *(const bf16x8*)(Vbh + (size_t)(ds2 * 16 + ln) * S_LEN + tj0 + kc * 32 + g * 8);

    // QK^T (swapped): S^T[key][q]
    f32x4 sc[4];
#pragma unroll
    for (int i = 0; i < 4; ++i) sc[i] = zero4;
    __builtin_amdgcn_s_setprio(1);
#pragma unroll
    for (int kc = 0; kc < 2; ++kc) {
      bf16x8 qf = kc ? qf1 : qf0;
#pragma unroll
      for (int mi = 0; mi < 4; ++mi) sc[mi] = MFMA16(kf[mi][kc], qf, sc[mi]);
    }
    __builtin_amdgcn_s_setprio(0);

    // prefetch next-tile K frags (covered by softmax + PV)
    if (t + 1 < t_hi) {
      const int nj0 = tj0 + 64;
#pragma unroll
      for (int mi = 0; mi < 4; ++mi)
#pragma unroll
        for (int kc = 0; kc < 2; ++kc)
          kf[mi][kc] = *(const bf16x8*)(Kbh + (size_t)(nj0 + mi * 16 + ln) * 64 + kc * 32 + g * 8);
    }

    // additive mask (pre-folded) + band check (uniform per-wave full/partial)
    f32x4 am[4];
#pragma unroll
    for (int mi = 0; mi < 4; ++mi) am[mi] = *(const f32x4*)(Ab + tj0 + mi * 16 + g * 4);
    float mt = -1e38f;
    const bool full = (t * 64 >= w * 16 + 15) && (t * 64 <= w * 16 + 449);
    if (full) {
#pragma unroll
      for (int mi = 0; mi < 4; ++mi)
#pragma unroll
        for (int r = 0; r < 4; ++r) {
          float v = sc[mi][r] + am[mi][r];
          sc[mi][r] = v;
          mt = fmaxf(mt, v);
        }
    } else {
#pragma unroll
      for (int mi = 0; mi < 4; ++mi)
#pragma unroll
        for (int r = 0; r < 4; ++r) {
          int j = tj0 + mi * 16 + g * 4 + r;
          bool valid = (j >= qg - 256) && (j <= qg + 256);
          float v = valid ? (sc[mi][r] + am[mi][r]) : NEGV;
          sc[mi][r] = v;
          mt = fmaxf(mt, v);
        }
    }
    mt = fmaxf(mt, __shfl_xor(mt, 16));
    mt = fmaxf(mt, __shfl_xor(mt, 32));
    // defer-max (T13)
    if (!__all(mt <= mrun + 8.f)) {
      float mnew = fmaxf(mrun, mt);
      float corr = __expf(mrun - mnew);
      lrun *= corr;
#pragma unroll
      for (int i = 0; i < 4; ++i) acc[i] *= corr;
      mrun = mnew;
    }
    float psum = 0.f;
    float pv[4][4];
#pragma unroll
    for (int mi = 0; mi < 4; ++mi)
#pragma unroll
      for (int r = 0; r < 4; ++r) {
        float p = __expf(sc[mi][r] - mrun);
        pv[mi][r] = p;
        psum += p;
      }
    psum += __shfl_xor(psum, 16);
    psum += __shfl_xor(psum, 32);
    lrun += psum;

    // P^T -> per-wave LDS [q][key], 8B-granule XOR swizzle (no barrier: same wave)
#pragma unroll
    for (int mi = 0; mi < 4; ++mi) {
      bf16x4 pk;
      pk[0] = (bf16)pv[mi][0]; pk[1] = (bf16)pv[mi][1];
      pk[2] = (bf16)pv[mi][2]; pk[3] = (bf16)pv[mi][3];
      *(bf16x4*)(&PtW[ln * 64 + ((mi * 4 + g) ^ ln) * 4]) = pk;
    }

    // PV: O^T[d][q] += V^T[d][key] * P^T[key][q]
    __builtin_amdgcn_s_setprio(1);
#pragma unroll
    for (int ds2 = 0; ds2 < 4; ++ds2) {
#pragma unroll
      for (int kc = 0; kc < 2; ++kc) {
        bf16x4 pa = *(const bf16x4*)(&PtW[ln * 64 + ((kc * 8 + g * 2) ^ ln) * 4]);
        bf16x4 pb = *(const bf16x4*)(&PtW[ln * 64 + ((kc * 8 + g * 2 + 1) ^ ln) * 4]);
        bf16x8 pf = __builtin_shufflevector(pa, pb, 0, 1, 2, 3, 4, 5, 6, 7);
        acc[ds2] = MFMA16(vf[ds2][kc], pf, acc[ds2]);
      }
    }
    __builtin_amdgcn_s_setprio(0);
  }

  float rl = 1.0f / lrun;
  if (imask[b * S_LEN + qg] != 0) rl = 0.0f;
  float* ob = out + ((size_t)b * S_LEN + qg) * EMB + h * 64;
#pragma unroll
  for (int ds2 = 0; ds2 < 4; ++ds2) {
    float4 o;
    o.x = acc[ds2][0] * rl; o.y = acc[ds2][1] * rl;
    o.z = acc[ds2][2] * rl; o.w = acc[ds2][3] * rl;
    *(float4*)(ob + ds2 * 16 + g * 4) = o;
  }
}

extern "C" void kernel_launch(void* const* d_in, const int* in_sizes, int n_in,
                              void* d_out, int out_size, void* d_ws, size_t ws_size,
                              hipStream_t stream) {
  const float* X = (const float*)d_in[0];
  const float* amask = (const float*)d_in[1];
  const unsigned char* imask = (const unsigned char*)d_in[2];
  const float* Wq = (const float*)d_in[3];
  const float* bq = (const float*)d_in[4];
  const float* Wk = (const float*)d_in[5];
  const float* bk = (const float*)d_in[6];
  const float* Wv = (const float*)d_in[7];
  const float* bv = (const float*)d_in[8];
  float* out = (float*)d_out;

  bf16* Xb = (bf16*)d_ws;                  //  8192*768
  bf16* Wb = Xb + 6291456;                 //  3*768*768 (Wq*0.125, Wk, Wv)
  bf16* Qb = Wb + 3 * 589824;              //  (b,h,s,d)
  bf16* Kb = Qb + 6291456;                 //  (b,h,s,d)
  bf16* Vt = Kb + 6291456;                 //  (b,h,d,s)
  float* Amadd = (float*)(Vt + 6291456);   //  B*S additive mask

  cvt_kernel<<<3072, 256, 0, stream>>>(X, Xb, 6291456 / 8, 1.0f);
  cvt3_kernel<<<dim3(288, 3), 256, 0, stream>>>(Wq, Wk, Wv, Wb, 589824 / 8);
  amask_cvt<<<32, 256, 0, stream>>>(amask, Amadd, 2 * S_LEN);
  qkv_gemm<<<dim3(64, 18), 256, 0, stream>>>(Xb, Wb, bq, bk, bv, Qb, Kb, Vt);
  attn_kernel<<<1536, 256, 0, stream>>>(Qb, Kb, Vt, Amadd, imask, out);
}

// Round 9
// 177.136 us; speedup vs baseline: 1.3886x; 1.3886x over previous
//
#include <hip/hip_runtime.h>

typedef __bf16 bf16;
typedef __attribute__((ext_vector_type(8))) __bf16 bf16x8;
typedef __attribute__((ext_vector_type(4))) __bf16 bf16x4;
typedef __attribute__((ext_vector_type(4))) float f32x4;

#define MFMA16(a, b, c) __builtin_amdgcn_mfma_f32_16x16x32_bf16((a), (b), (c), 0, 0, 0)

#define S_LEN 4096
#define NHEAD 12
#define EMB   768
#define NEGV  (-1e30f)

// async global->LDS, 16B per lane. LDS dest = wave-uniform base + lane*16 (linear);
// swizzled layouts are achieved by pre-swizzling the per-lane GLOBAL source addr.
__device__ __forceinline__ void gload16(const bf16* g, bf16* l) {
  __builtin_amdgcn_global_load_lds((const __attribute__((address_space(1))) void*)g,
                                   (__attribute__((address_space(3))) void*)l, 16, 0, 0);
}

// ---------------- kernel 0: f32 -> bf16 convert (optionally scaled) -------------
__global__ __launch_bounds__(256) void cvt_kernel(const float* __restrict__ x,
                                                  bf16* __restrict__ o, int n8, float scale) {
  int i = blockIdx.x * 256 + threadIdx.x;
  if (i >= n8) return;
  const float4* p = (const float4*)(x + (size_t)i * 8);
  float4 a = p[0], b = p[1];
  bf16x8 v;
  v[0] = (bf16)(a.x * scale); v[1] = (bf16)(a.y * scale);
  v[2] = (bf16)(a.z * scale); v[3] = (bf16)(a.w * scale);
  v[4] = (bf16)(b.x * scale); v[5] = (bf16)(b.y * scale);
  v[6] = (bf16)(b.z * scale); v[7] = (bf16)(b.w * scale);
  *(bf16x8*)(o + (size_t)i * 8) = v;
}

// three weight matrices in one launch; which = blockIdx.y, Wq gets 1/sqrt(D) folded
__global__ __launch_bounds__(256) void cvt3_kernel(const float* __restrict__ w0,
                                                   const float* __restrict__ w1,
                                                   const float* __restrict__ w2,
                                                   bf16* __restrict__ o, int n8) {
  int which = blockIdx.y;
  const float* src = (which == 0) ? w0 : (which == 1) ? w1 : w2;
  float scale = (which == 0) ? 0.125f : 1.0f;
  int i = blockIdx.x * 256 + threadIdx.x;
  if (i >= n8) return;
  const float4* p = (const float4*)(src + (size_t)i * 8);
  float4 a = p[0], b = p[1];
  bf16x8 v;
  v[0] = (bf16)(a.x * scale); v[1] = (bf16)(a.y * scale);
  v[2] = (bf16)(a.z * scale); v[3] = (bf16)(a.w * scale);
  v[4] = (bf16)(b.x * scale); v[5] = (bf16)(b.y * scale);
  v[6] = (bf16)(b.z * scale); v[7] = (bf16)(b.w * scale);
  *(bf16x8*)(o + ((size_t)which * n8 + i) * 8) = v;
}

// attention_mask -> additive float (-1e30 where masked, 0 elsewhere)
__global__ __launch_bounds__(256) void amask_cvt(const float* __restrict__ am,
                                                 float* __restrict__ o, int n) {
  int i = blockIdx.x * 256 + threadIdx.x;
  if (i < n) o[i] = (am[i] != 0.f) ? -1e30f : 0.f;
}

// ---------------- kernel 1: fused QKV GEMM  out = X @ W^T + bias ----------------
// 128x128 tile, BK=64, 4 waves. Double-buffered global_load_lds staging (T3-min
// 2-phase): stage(t+1) issued BEFORE compute(t); ONE __syncthreads per K-step,
// after the MFMAs — loads fly during compute. Vectorized LDS epilogue.
__global__ __launch_bounds__(256) void qkv_gemm(const bf16* __restrict__ Xb, const bf16* __restrict__ Wb,
                                                const float* __restrict__ bq, const float* __restrict__ bk,
                                                const float* __restrict__ bv,
                                                bf16* __restrict__ Qo, bf16* __restrict__ Ko,
                                                bf16* __restrict__ Vt) {
  __shared__ union SM {
    struct { bf16 a[2][128 * 64]; bf16 b2[2][128 * 64]; } st;  // 64KB double-buffered staging
    bf16 c[128 * 130];                                          // epilogue buffer (overlaps)
  } sm;
  const int tid = threadIdx.x;
  const int l = tid & 63, w = tid >> 6;
  const int ln = l & 15, g = l >> 4;
  const int wm = w >> 1, wn = w & 1;
  const int m0 = blockIdx.x * 128;
  const int n0 = blockIdx.y * 128;

  const f32x4 zero4 = {0.f, 0.f, 0.f, 0.f};
  f32x4 acc[4][4];
#pragma unroll
  for (int i = 0; i < 4; ++i)
#pragma unroll
    for (int j = 0; j < 4; ++j) acc[i][j] = zero4;

  int srow[4], sslot[4];
#pragma unroll
  for (int i = 0; i < 4; ++i) {
    const int G = w * 256 + i * 64 + l;      // granule id 0..1023
    srow[i] = G >> 3;
    sslot[i] = (G & 7) ^ (srow[i] & 7);
  }

  auto stage = [&](int sb, int kt) {
    const int k0 = kt * 64;
#pragma unroll
    for (int i = 0; i < 4; ++i) {
      gload16(Xb + (size_t)(m0 + srow[i]) * 768 + k0 + sslot[i] * 8, &sm.st.a[sb][(w * 256 + i * 64) * 8]);
      gload16(Wb + (size_t)(n0 + srow[i]) * 768 + k0 + sslot[i] * 8, &sm.st.b2[sb][(w * 256 + i * 64) * 8]);
    }
  };

  stage(0, 0);
  __syncthreads();

  int buf = 0;
  for (int kt = 0; kt < 12; ++kt, buf ^= 1) {
    if (kt < 11) stage(buf ^ 1, kt + 1);
#pragma unroll
    for (int kc = 0; kc < 2; ++kc) {
      bf16x8 af[4], bfr[4];
#pragma unroll
      for (int i = 0; i < 4; ++i) {
        int ra = wm * 64 + i * 16 + ln;
        af[i] = *(const bf16x8*)(&sm.st.a[buf][ra * 64 + ((kc * 4 + g) ^ (ra & 7)) * 8]);
        int rb = wn * 64 + i * 16 + ln;
        bfr[i] = *(const bf16x8*)(&sm.st.b2[buf][rb * 64 + ((kc * 4 + g) ^ (rb & 7)) * 8]);
      }
#pragma unroll
      for (int mi = 0; mi < 4; ++mi)
#pragma unroll
        for (int ni = 0; ni < 4; ++ni)
          acc[mi][ni] = MFMA16(af[mi], bfr[ni], acc[mi][ni]);
    }
    __syncthreads();
  }

  // ----- epilogue: all outputs through LDS, vectorized stores -----
  const int which = n0 / 768;           // 0=Q 1=K 2=V
  const int h0 = (n0 % 768) >> 6;
  const int b = m0 >> 12;
  const int h = h0 + wn;
  const float bsc = (which == 0) ? 0.125f : 1.0f;
  const float* bias = (which == 0) ? bq : (which == 1) ? bk : bv;
  float bvv[4];
#pragma unroll
  for (int ni = 0; ni < 4; ++ni) bvv[ni] = bias[h * 64 + ni * 16 + ln] * bsc;

#pragma unroll
  for (int mi = 0; mi < 4; ++mi)
#pragma unroll
    for (int ni = 0; ni < 4; ++ni)
#pragma unroll
      for (int r = 0; r < 4; ++r) {
        int sl = wm * 64 + mi * 16 + g * 4 + r;
        sm.c[sl * 130 + wn * 64 + ni * 16 + ln] = (bf16)(acc[mi][ni][r] + bvv[ni]);
      }
  __syncthreads();

  if (which < 2) {
    bf16* dst = (which == 0) ? Qo : Ko;
#pragma unroll
    for (int it = 0; it < 8; ++it) {
      int gid = it * 256 + tid;
      int sl = gid >> 4, cg = gid & 15;
      int hh = h0 + (cg >> 3);
      bf16x8 v8 = *(const bf16x8*)(&sm.c[sl * 130 + cg * 8]);
      *(bf16x8*)(dst + ((size_t)(b * NHEAD + hh) * S_LEN + (m0 & 4095) + sl) * 64 + (cg & 7) * 8) = v8;
    }
  } else {
#pragma unroll
    for (int it = 0; it < 4; ++it) {
      int d = it * 32 + (tid >> 3);
      int scp = tid & 7;
      int hh = h0 + (d >> 6);
      bf16x8 o0, o1;
#pragma unroll
      for (int i2 = 0; i2 < 8; ++i2) o0[i2] = sm.c[(scp * 16 + i2) * 130 + d];
#pragma unroll
      for (int i2 = 0; i2 < 8; ++i2) o1[i2] = sm.c[(scp * 16 + 8 + i2) * 130 + d];
      bf16* dp = Vt + ((size_t)(b * NHEAD + hh) * 64 + (d & 63)) * S_LEN + (m0 & 4095) + scp * 16;
      *(bf16x8*)dp = o0;
      *(bf16x8*)(dp + 8) = o1;
    }
  }
}

// ---------------- kernel 2: banded flash attention ----------------
// Round-4 proven skeleton: 128 q x (b,h) block, 8 waves, double-buffered K/V via
// global_load_lds, XCD-bijective swizzle, P^T via per-wave LDS (PROVEN path —
// the round-7 shuffle exchange was provably wrong: __shfl evaluates the operand
// on the SOURCE lane, so source g'=0 cannot serve dest g=0 (needs lo) and g=2
// (needs hi) with one pre-selected variable).
// Changes vs round-4 (safe subset):
//  - additive mask as direct f32x4 global loads issued BEFORE the stage
//    gload16s: softmax's wait on am is vmcnt(16), leaving the K/V prefetch in
//    flight through PV (vmcnt is in-order; am older than stage).
//  - explicit vmcnt(0) + raw s_barrier at loop end (skips __syncthreads'
//    lgkmcnt drain; P^T LDS is wave-private so no cross-wave hazard).
__global__ __launch_bounds__(512) void attn_kernel(const bf16* __restrict__ Qb, const bf16* __restrict__ Kb,
                                                   const bf16* __restrict__ Vtb,
                                                   const float* __restrict__ Amadd,
                                                   const unsigned char* __restrict__ imask,
                                                   float* __restrict__ out) {
  __shared__ bf16 Ks[2][64 * 64];    // [key][dim], swizzled content
  __shared__ bf16 Vs[2][64 * 64];    // [dim][key], swizzled content
  __shared__ bf16 Pt[8][16 * 64];    // per-wave P^T [q][key], 8B-granule XOR swizzle
  const int tid = threadIdx.x;
  const int l = tid & 63, w = tid >> 6;
  const int ln = l & 15, g = l >> 4;
  // XCD swizzle: 768 blocks = 8 * 96, bijective
  const int orig = blockIdx.x;
  const int lb = (orig & 7) * 96 + (orig >> 3);
  const int qc = lb & 31, bh = lb >> 5;
  const int b = bh / NHEAD, h = bh % NHEAD;
  const int q0 = qc * 128;
  const int qg = q0 + w * 16 + ln;

  const size_t qoff = ((size_t)bh * S_LEN + qg) * 64;
  const bf16x8 qf0 = *(const bf16x8*)(Qb + qoff + g * 8);
  const bf16x8 qf1 = *(const bf16x8*)(Qb + qoff + 32 + g * 8);
  const float* Ab = Amadd + b * S_LEN;

  const f32x4 zero4 = {0.f, 0.f, 0.f, 0.f};
  f32x4 acc[4];
#pragma unroll
  for (int i = 0; i < 4; ++i) acc[i] = zero4;
  float mrun = -1e38f, lrun = 0.f;

  const int t_lo = (q0 >= 256) ? 0 : ((256 - q0) >> 6);
  int t_hi = (S_LEN + 256 - q0) >> 6;
  if (t_hi > 10) t_hi = 10;

  auto stage = [&](int sb, int t) {
    const int tj0 = q0 - 256 + t * 64;
    const int G = w * 64 + l;                  // granule 0..511 (8 waves x 64)
    const int row = G >> 3, dsl = G & 7;
    const int slot = dsl ^ (row & 7);
    gload16(Kb + ((size_t)bh * S_LEN + tj0 + row) * 64 + slot * 8, &Ks[sb][w * 512]);
    gload16(Vtb + ((size_t)bh * 64 + row) * S_LEN + tj0 + slot * 8, &Vs[sb][w * 512]);
  };

  stage(0, t_lo);
  asm volatile("s_waitcnt vmcnt(0)" ::: "memory");
  __syncthreads();

  int buf = 0;
  for (int t = t_lo; t < t_hi; ++t, buf ^= 1) {
    const int tj0 = q0 - 256 + t * 64;

    // additive mask for THIS tile, issued before the stage loads (older in the
    // vmcnt queue -> softmax's am wait leaves the prefetch in flight)
    f32x4 am[4];
#pragma unroll
    for (int mi = 0; mi < 4; ++mi) am[mi] = *(const f32x4*)(Ab + tj0 + mi * 16 + g * 4);

    if (t + 1 < t_hi) stage(buf ^ 1, t + 1);   // prefetch overlaps compute

    // QK^T (swapped): S^T[key][q]
    f32x4 sc[4];
#pragma unroll
    for (int i = 0; i < 4; ++i) sc[i] = zero4;
    __builtin_amdgcn_s_setprio(1);
#pragma unroll
    for (int kc = 0; kc < 2; ++kc) {
      bf16x8 qf = kc ? qf1 : qf0;
#pragma unroll
      for (int mi = 0; mi < 4; ++mi) {
        int r = mi * 16 + ln;
        bf16x8 kf = *(const bf16x8*)(&Ks[buf][r * 64 + ((kc * 4 + g) ^ (r & 7)) * 8]);
        sc[mi] = MFMA16(kf, qf, sc[mi]);
      }
    }
    __builtin_amdgcn_s_setprio(0);

    // mask + online softmax. Band check only on (uniform per-wave) partial tiles.
    float mt = -1e38f;
    const bool full = (t * 64 >= w * 16 + 15) && (t * 64 <= w * 16 + 449);
    if (full) {
#pragma unroll
      for (int mi = 0; mi < 4; ++mi)
#pragma unroll
        for (int r = 0; r < 4; ++r) {
          float v = sc[mi][r] + am[mi][r];
          sc[mi][r] = v;
          mt = fmaxf(mt, v);
        }
    } else {
#pragma unroll
      for (int mi = 0; mi < 4; ++mi)
#pragma unroll
        for (int r = 0; r < 4; ++r) {
          int j = tj0 + mi * 16 + g * 4 + r;
          bool valid = (j >= qg - 256) && (j <= qg + 256);
          float v = valid ? (sc[mi][r] + am[mi][r]) : NEGV;
          sc[mi][r] = v;
          mt = fmaxf(mt, v);
        }
    }
    mt = fmaxf(mt, __shfl_xor(mt, 16));
    mt = fmaxf(mt, __shfl_xor(mt, 32));
    // defer-max (T13): only rescale when the tile max moved by > 8
    if (!__all(mt <= mrun + 8.f)) {
      float mnew = fmaxf(mrun, mt);
      float corr = __expf(mrun - mnew);
      lrun *= corr;
#pragma unroll
      for (int i = 0; i < 4; ++i) acc[i] *= corr;
      mrun = mnew;
    }
    float psum = 0.f;
    float pv[4][4];
#pragma unroll
    for (int mi = 0; mi < 4; ++mi)
#pragma unroll
      for (int r = 0; r < 4; ++r) {
        float p = __expf(sc[mi][r] - mrun);
        pv[mi][r] = p;
        psum += p;
      }
    psum += __shfl_xor(psum, 16);
    psum += __shfl_xor(psum, 32);
    lrun += psum;

    // P^T -> per-wave LDS [q][key], 8B-granule XOR swizzle (wave-private)
    bf16* PtW = &Pt[w][0];
#pragma unroll
    for (int mi = 0; mi < 4; ++mi) {
      bf16x4 pk;
      pk[0] = (bf16)pv[mi][0]; pk[1] = (bf16)pv[mi][1];
      pk[2] = (bf16)pv[mi][2]; pk[3] = (bf16)pv[mi][3];
      *(bf16x4*)(&PtW[ln * 64 + ((mi * 4 + g) ^ ln) * 4]) = pk;
    }

    // PV: O^T[d][q] += V^T[d][key] * P^T[key][q]
    __builtin_amdgcn_s_setprio(1);
#pragma unroll
    for (int ds2 = 0; ds2 < 4; ++ds2) {
#pragma unroll
      for (int kc = 0; kc < 2; ++kc) {
        int r = ds2 * 16 + ln;
        bf16x8 vf = *(const bf16x8*)(&Vs[buf][r * 64 + ((kc * 4 + g) ^ (r & 7)) * 8]);
        bf16x4 pa = *(const bf16x4*)(&PtW[ln * 64 + ((kc * 8 + g * 2) ^ ln) * 4]);
        bf16x4 pb = *(const bf16x4*)(&PtW[ln * 64 + ((kc * 8 + g * 2 + 1) ^ ln) * 4]);
        bf16x8 pf = __builtin_shufflevector(pa, pb, 0, 1, 2, 3, 4, 5, 6, 7);
        acc[ds2] = MFMA16(vf, pf, acc[ds2]);
      }
    }
    __builtin_amdgcn_s_setprio(0);

    // drain prefetch, then barrier (no lgkmcnt drain needed: P^T is wave-private)
    asm volatile("s_waitcnt vmcnt(0)" ::: "memory");
    __builtin_amdgcn_s_barrier();
    __builtin_amdgcn_sched_barrier(0);
  }

  float rl = 1.0f / lrun;
  if (imask[b * S_LEN + qg] != 0) rl = 0.0f;
  float* ob = out + ((size_t)b * S_LEN + qg) * EMB + h * 64;
#pragma unroll
  for (int ds2 = 0; ds2 < 4; ++ds2) {
    float4 o;
    o.x = acc[ds2][0] * rl; o.y = acc[ds2][1] * rl;
    o.z = acc[ds2][2] * rl; o.w = acc[ds2][3] * rl;
    *(float4*)(ob + ds2 * 16 + g * 4) = o;
  }
}

extern "C" void kernel_launch(void* const* d_in, const int* in_sizes, int n_in,
                              void* d_out, int out_size, void* d_ws, size_t ws_size,
                              hipStream_t stream) {
  const float* X = (const float*)d_in[0];
  const float* amask = (const float*)d_in[1];
  const unsigned char* imask = (const unsigned char*)d_in[2];
  const float* Wq = (const float*)d_in[3];
  const float* bq = (const float*)d_in[4];
  const float* Wk = (const float*)d_in[5];
  const float* bk = (const float*)d_in[6];
  const float* Wv = (const float*)d_in[7];
  const float* bv = (const float*)d_in[8];
  float* out = (float*)d_out;

  bf16* Xb = (bf16*)d_ws;                  //  8192*768
  bf16* Wb = Xb + 6291456;                 //  3*768*768 (Wq*0.125, Wk, Wv)
  bf16* Qb = Wb + 3 * 589824;              //  (b,h,s,d)
  bf16* Kb = Qb + 6291456;                 //  (b,h,s,d)
  bf16* Vt = Kb + 6291456;                 //  (b,h,d,s)
  float* Amadd = (float*)(Vt + 6291456);   //  B*S additive mask

  cvt_kernel<<<3072, 256, 0, stream>>>(X, Xb, 6291456 / 8, 1.0f);
  cvt3_kernel<<<dim3(288, 3), 256, 0, stream>>>(Wq, Wk, Wv, Wb, 589824 / 8);
  amask_cvt<<<32, 256, 0, stream>>>(amask, Amadd, 2 * S_LEN);
  qkv_gemm<<<dim3(64, 18), 256, 0, stream>>>(Xb, Wb, bq, bk, bv, Qb, Kb, Vt);
  attn_kernel<<<768, 512, 0, stream>>>(Qb, Kb, Vt, Amadd, imask, out);
}